// Round 1
// baseline (226.810 us; speedup 1.0000x reference)
//
#include <hip/hip_runtime.h>
#include <cstdint>
#include <cstddef>

#define B_ROWS 16384
#define D_DIM  512
#define O_DIM  512
#define K_DIM  4608    // 9 * 512: f=0 silu, f=1..8 spline basis
#define BM 128
#define BN 128
#define BK 32

typedef __bf16 bf16;
typedef __attribute__((ext_vector_type(8))) bf16  bf16x8;
typedef __attribute__((ext_vector_type(4))) float f32x4;

__device__ __forceinline__ void async_load16(const void* g, void* l) {
    __builtin_amdgcn_global_load_lds(
        (const __attribute__((address_space(1))) void*)g,
        (__attribute__((address_space(3))) void*)l,
        16, 0, 0);
}

// x[B,512] fp32 -> A[nrows, 4608] bf16, feature-major layout k = f*512 + i
__global__ void featurize_kernel(const float* __restrict__ x,
                                 bf16* __restrict__ A,
                                 int row_start, int nrows) {
    int idx = blockIdx.x * blockDim.x + threadIdx.x;
    if (idx >= nrows * D_DIM) return;
    int br = idx >> 9;           // local row
    int i  = idx & 511;
    int b  = row_start + br;
    float xv = x[(size_t)b * D_DIM + i];

    // silu
    float s = xv / (1.0f + __expf(-xv));

    // uniform cubic B-spline, knots g[j] = 0.4*j - 3.2 (j=0..11)
    float xn = fminf(fmaxf(xv, -2.0f), 2.0f);
    float t  = (xn + 3.2f) * 2.5f;      // /h
    float ft = floorf(t);
    int   j0 = (int)ft;                 // knot interval index
    float u  = t - ft;
    float u2 = u * u, u3 = u2 * u;
    float omu = 1.0f - u;
    const float s6 = 1.0f / 6.0f;
    float w0 = omu * omu * omu * s6;                         // basis j0-3
    float w1 = (3.0f * u3 - 6.0f * u2 + 4.0f) * s6;          // basis j0-2
    float w2 = (-3.0f * u3 + 3.0f * u2 + 3.0f * u + 1.0f) * s6; // basis j0-1
    float w3 = u3 * s6;                                      // basis j0
    bool valid = (j0 >= 3) && (j0 <= 10);   // x in [-2, 1.2): else all-zero (matches ref)
    int base = j0 - 3;

    bf16* row = A + (size_t)br * K_DIM + i;
    row[0] = (bf16)s;
#pragma unroll
    for (int j = 0; j < 8; j++) {
        int c = j - base;
        float v = 0.0f;
        if (valid)
            v = (c == 0) ? w0 : (c == 1) ? w1 : (c == 2) ? w2 : (c == 3) ? w3 : 0.0f;
        row[(size_t)(j + 1) * D_DIM] = (bf16)v;
    }
}

// base_weight[O,D] + spline_weight[O,D,8] fp32 -> W[O, 4608] bf16 (same k layout)
__global__ void pack_w_kernel(const float* __restrict__ bw,
                              const float* __restrict__ sw,
                              bf16* __restrict__ W) {
    int idx = blockIdx.x * blockDim.x + threadIdx.x;   // over O*D
    if (idx >= O_DIM * D_DIM) return;
    int i = idx & 511;
    int o = idx >> 9;
    bf16* row = W + (size_t)o * K_DIM + i;
    row[0] = (bf16)bw[idx];
    const float* sp = sw + (size_t)idx * 8;
#pragma unroll
    for (int c = 0; c < 8; c++)
        row[(size_t)(c + 1) * D_DIM] = (bf16)sp[c];
}

// C[M,512] fp32 = A[M,4608] @ W[512,4608]^T   (m97 structure: 128x128 tile,
// 4 waves of 64x64, BK=32, global_load_lds width-16, mfma 16x16x32 bf16)
__global__ __launch_bounds__(256, 2)
void gemm_bt_kernel(const bf16* __restrict__ A, const bf16* __restrict__ W,
                    float* __restrict__ C) {
    __shared__ __align__(16) bf16 As[BM * BK];   // 8 KB
    __shared__ __align__(16) bf16 Bs[BN * BK];   // 8 KB

    const int tid  = threadIdx.x;
    const int n0   = blockIdx.x * BN;
    const int m0   = blockIdx.y * BM;
    const int wave = tid >> 6;
    const int lane = tid & 63;
    const int wm   = (wave & 1) * 64;
    const int wn   = (wave >> 1) * 64;
    const int l15  = lane & 15;
    const int quad = lane >> 4;

    // staging: thread covers 8-bf16 chunks tid and tid+256
    const int sr = tid >> 2;            // 0..63
    const int sc = (tid & 3) * 8;       // 0,8,16,24
    const bf16* gA0 = A + (size_t)(m0 + sr) * K_DIM + sc;
    const bf16* gA1 = gA0 + (size_t)64 * K_DIM;
    const bf16* gB0 = W + (size_t)(n0 + sr) * K_DIM + sc;
    const bf16* gB1 = gB0 + (size_t)64 * K_DIM;
    bf16* lA0 = As + tid * 8;
    bf16* lA1 = As + tid * 8 + 2048;
    bf16* lB0 = Bs + tid * 8;
    bf16* lB1 = Bs + tid * 8 + 2048;

    const int aoff = (wm + l15) * BK + quad * 8;
    const int boff = (wn + l15) * BK + quad * 8;

    f32x4 acc[4][4] = {};

    for (int k0 = 0; k0 < K_DIM; k0 += BK) {
        async_load16(gA0 + k0, lA0);
        async_load16(gA1 + k0, lA1);
        async_load16(gB0 + k0, lB0);
        async_load16(gB1 + k0, lB1);
        __syncthreads();   // compiler drains vmcnt before s_barrier

        bf16x8 af[4], bfr[4];
#pragma unroll
        for (int tt = 0; tt < 4; tt++)
            af[tt] = *(const bf16x8*)(As + aoff + tt * 16 * BK);
#pragma unroll
        for (int tt = 0; tt < 4; tt++)
            bfr[tt] = *(const bf16x8*)(Bs + boff + tt * 16 * BK);

#pragma unroll
        for (int im = 0; im < 4; im++)
#pragma unroll
            for (int jn = 0; jn < 4; jn++)
                acc[im][jn] = __builtin_amdgcn_mfma_f32_16x16x32_bf16(
                    af[im], bfr[jn], acc[im][jn], 0, 0, 0);
        __syncthreads();
    }

    // C/D layout: col = lane&15, row = quad*4 + reg   [measured m89/m91]
#pragma unroll
    for (int im = 0; im < 4; im++) {
        const int rbase = m0 + wm + im * 16 + quad * 4;
#pragma unroll
        for (int jn = 0; jn < 4; jn++) {
            const int col = n0 + wn + jn * 16 + l15;
#pragma unroll
            for (int r = 0; r < 4; r++)
                C[(size_t)(rbase + r) * O_DIM + col] = acc[im][jn][r];
        }
    }
}

extern "C" void kernel_launch(void* const* d_in, const int* in_sizes, int n_in,
                              void* d_out, int out_size, void* d_ws, size_t ws_size,
                              hipStream_t stream) {
    const float* x  = (const float*)d_in[0];
    const float* bw = (const float*)d_in[1];
    const float* sw = (const float*)d_in[2];
    float* out = (float*)d_out;

    const size_t Wbytes = (size_t)O_DIM * K_DIM * sizeof(bf16);  // 4.7 MB (16B-aligned)
    bf16* W = (bf16*)d_ws;
    bf16* A = (bf16*)((char*)d_ws + Wbytes);

    size_t avail = (ws_size > Wbytes) ? (ws_size - Wbytes) : 0;
    long long mr = (long long)(avail / ((size_t)K_DIM * sizeof(bf16)));
    int max_rows = (int)((mr / BM) * BM);
    if (max_rows <= 0) return;  // workspace too small to run at all
    if (max_rows > B_ROWS) max_rows = B_ROWS;

    pack_w_kernel<<<(O_DIM * D_DIM + 255) / 256, 256, 0, stream>>>(bw, sw, W);
    for (int r0 = 0; r0 < B_ROWS; r0 += max_rows) {
        int rows = B_ROWS - r0;
        if (rows > max_rows) rows = max_rows;
        featurize_kernel<<<(rows * D_DIM + 255) / 256, 256, 0, stream>>>(x, A, r0, rows);
        gemm_bt_kernel<<<dim3(O_DIM / BN, rows / BM), 256, 0, stream>>>(
            A, W, out + (size_t)r0 * O_DIM);
    }
}

// Round 2
// 221.244 us; speedup vs baseline: 1.0252x; 1.0252x over previous
//
#include <hip/hip_runtime.h>
#include <cstdint>
#include <cstddef>

#define B_ROWS 16384
#define D_DIM  512
#define O_DIM  512
#define K_DIM  4608    // 9 * 512: f=0 silu, f=1..8 spline basis
#define BM 128
#define BN 128
#define BK 32

typedef __bf16 bf16;
typedef __attribute__((ext_vector_type(8))) bf16  bf16x8;
typedef __attribute__((ext_vector_type(4))) float f32x4;

__device__ __forceinline__ void async_load16(const void* g, void* l) {
    __builtin_amdgcn_global_load_lds(
        (const __attribute__((address_space(1))) void*)g,
        (__attribute__((address_space(3))) void*)l,
        16, 0, 0);
}

// x[B,512] fp32 -> A[nrows, 4608] bf16, layout k = f*512 + i.
// One thread per 8 consecutive i: 2x float4 load, 9x bf16x8 (16B) stores
// -> 1 KiB/wave per store instruction (was 128 B with scalar bf16 stores).
__global__ void featurize_kernel(const float* __restrict__ x,
                                 bf16* __restrict__ A,
                                 int row_start, int nrows) {
    int idx = blockIdx.x * blockDim.x + threadIdx.x;   // over nrows * 64
    if (idx >= nrows * 64) return;
    int br = idx >> 6;
    int i0 = (idx & 63) * 8;

    const float4* xp = (const float4*)(x + (size_t)(row_start + br) * D_DIM + i0);
    float4 xa = xp[0], xb = xp[1];
    float xv[8] = {xa.x, xa.y, xa.z, xa.w, xb.x, xb.y, xb.z, xb.w};

    bf16 ob[9][8];
#pragma unroll
    for (int e = 0; e < 8; e++) {
        float xvv = xv[e];
        float s = xvv / (1.0f + __expf(-xvv));
        ob[0][e] = (bf16)s;

        // uniform cubic B-spline, knots g[j] = 0.4*j - 3.2 (j=0..11)
        float xn = fminf(fmaxf(xvv, -2.0f), 2.0f);
        float t  = (xn + 3.2f) * 2.5f;
        float ft = floorf(t);
        int   j0 = (int)ft;
        float u  = t - ft;
        float u2 = u * u, u3 = u2 * u;
        float omu = 1.0f - u;
        const float s6 = 1.0f / 6.0f;
        float w0 = omu * omu * omu * s6;
        float w1 = (3.0f * u3 - 6.0f * u2 + 4.0f) * s6;
        float w2 = (-3.0f * u3 + 3.0f * u2 + 3.0f * u + 1.0f) * s6;
        float w3 = u3 * s6;
        bool valid = (j0 >= 3) && (j0 <= 10);   // x in [-2,1.2); else all-zero (matches ref)
        int base = j0 - 3;
#pragma unroll
        for (int j = 0; j < 8; j++) {
            int c = j - base;
            float v = 0.0f;
            if (valid)
                v = (c == 0) ? w0 : (c == 1) ? w1 : (c == 2) ? w2 : (c == 3) ? w3 : 0.0f;
            ob[j + 1][e] = (bf16)v;
        }
    }

    bf16* row = A + (size_t)br * K_DIM + i0;
#pragma unroll
    for (int f = 0; f < 9; f++)
        *(bf16x8*)(row + (size_t)f * D_DIM) = *(const bf16x8*)ob[f];
}

// base_weight[O,D] + spline_weight[O,D,8] fp32 -> W[O, 4608] bf16 (same k layout)
// One thread per 8 consecutive i, vectorized 16B stores.
__global__ void pack_w_kernel(const float* __restrict__ bw,
                              const float* __restrict__ sw,
                              bf16* __restrict__ W) {
    int idx = blockIdx.x * blockDim.x + threadIdx.x;   // over O*64
    if (idx >= O_DIM * 64) return;
    int o  = idx >> 6;
    int i0 = (idx & 63) * 8;

    bf16 ob[9][8];
    const float* bwp = bw + (size_t)o * D_DIM + i0;
#pragma unroll
    for (int e = 0; e < 8; e++) {
        ob[0][e] = (bf16)bwp[e];
        const float* sp = sw + ((size_t)o * D_DIM + i0 + e) * 8;
#pragma unroll
        for (int c = 0; c < 8; c++)
            ob[c + 1][e] = (bf16)sp[c];
    }
    bf16* row = W + (size_t)o * K_DIM + i0;
#pragma unroll
    for (int f = 0; f < 9; f++)
        *(bf16x8*)(row + (size_t)f * D_DIM) = *(const bf16x8*)ob[f];
}

// C[M,512] fp32 = A[M,4608] @ W[512,4608]^T
// m97 structure + XOR-swizzled LDS chunk layout:
//   LDS[row][slot] holds global chunk (slot ^ ((row>>1)&3)); writer permutes
//   the GLOBAL source per lane (LDS dest stays lane-contiguous as
//   global_load_lds requires); reader XORs quad with (l15>>1)&3 -- this term
//   is fragment-invariant since wm and tt*16 are =0 mod 4 after >>1.
//   Result: 2 rows per chunk-slot per 16-bank half -> 2-way aliasing (free)
//   instead of 8-way.
__global__ __launch_bounds__(256, 2)
void gemm_bt_kernel(const bf16* __restrict__ A, const bf16* __restrict__ W,
                    float* __restrict__ C) {
    __shared__ __align__(16) bf16 As[BM * BK];   // 8 KB
    __shared__ __align__(16) bf16 Bs[BN * BK];   // 8 KB

    const int tid  = threadIdx.x;
    const int n0   = blockIdx.x * BN;
    const int m0   = blockIdx.y * BM;
    const int wave = tid >> 6;
    const int lane = tid & 63;
    const int wm   = (wave & 1) * 64;
    const int wn   = (wave >> 1) * 64;
    const int l15  = lane & 15;
    const int quad = lane >> 4;

    // staging: thread covers LDS slot (sr, tid&3); global chunk is XOR-swizzled
    const int sr    = tid >> 2;                         // 0..63
    const int sc    = ((tid & 3) ^ ((sr >> 1) & 3)) * 8;  // swizzled global chunk
    const bf16* gA0 = A + (size_t)(m0 + sr) * K_DIM + sc;
    const bf16* gA1 = gA0 + (size_t)64 * K_DIM;
    const bf16* gB0 = W + (size_t)(n0 + sr) * K_DIM + sc;
    const bf16* gB1 = gB0 + (size_t)64 * K_DIM;
    bf16* lA0 = As + tid * 8;
    bf16* lA1 = As + tid * 8 + 2048;
    bf16* lB0 = Bs + tid * 8;
    bf16* lB1 = Bs + tid * 8 + 2048;

    const int swz  = (l15 >> 1) & 3;
    const int aoff = (wm + l15) * BK + (quad ^ swz) * 8;
    const int boff = (wn + l15) * BK + (quad ^ swz) * 8;

    f32x4 acc[4][4] = {};

    for (int k0 = 0; k0 < K_DIM; k0 += BK) {
        async_load16(gA0 + k0, lA0);
        async_load16(gA1 + k0, lA1);
        async_load16(gB0 + k0, lB0);
        async_load16(gB1 + k0, lB1);
        __syncthreads();   // compiler drains vmcnt before s_barrier

        bf16x8 af[4], bfr[4];
#pragma unroll
        for (int tt = 0; tt < 4; tt++)
            af[tt] = *(const bf16x8*)(As + aoff + tt * 16 * BK);
#pragma unroll
        for (int tt = 0; tt < 4; tt++)
            bfr[tt] = *(const bf16x8*)(Bs + boff + tt * 16 * BK);

#pragma unroll
        for (int im = 0; im < 4; im++)
#pragma unroll
            for (int jn = 0; jn < 4; jn++)
                acc[im][jn] = __builtin_amdgcn_mfma_f32_16x16x32_bf16(
                    af[im], bfr[jn], acc[im][jn], 0, 0, 0);
        __syncthreads();
    }

    // C/D layout: col = lane&15, row = quad*4 + reg   [measured m89/m91]
#pragma unroll
    for (int im = 0; im < 4; im++) {
        const int rbase = m0 + wm + im * 16 + quad * 4;
#pragma unroll
        for (int jn = 0; jn < 4; jn++) {
            const int col = n0 + wn + jn * 16 + l15;
#pragma unroll
            for (int r = 0; r < 4; r++)
                C[(size_t)(rbase + r) * O_DIM + col] = acc[im][jn][r];
        }
    }
}

extern "C" void kernel_launch(void* const* d_in, const int* in_sizes, int n_in,
                              void* d_out, int out_size, void* d_ws, size_t ws_size,
                              hipStream_t stream) {
    const float* x  = (const float*)d_in[0];
    const float* bw = (const float*)d_in[1];
    const float* sw = (const float*)d_in[2];
    float* out = (float*)d_out;

    const size_t Wbytes = (size_t)O_DIM * K_DIM * sizeof(bf16);  // 4.7 MB (16B-aligned)
    bf16* W = (bf16*)d_ws;
    bf16* A = (bf16*)((char*)d_ws + Wbytes);

    size_t avail = (ws_size > Wbytes) ? (ws_size - Wbytes) : 0;
    long long mr = (long long)(avail / ((size_t)K_DIM * sizeof(bf16)));
    int max_rows = (int)((mr / BM) * BM);
    if (max_rows <= 0) return;  // workspace too small to run at all
    if (max_rows > B_ROWS) max_rows = B_ROWS;

    pack_w_kernel<<<(O_DIM * 64 + 255) / 256, 256, 0, stream>>>(bw, sw, W);
    for (int r0 = 0; r0 < B_ROWS; r0 += max_rows) {
        int rows = B_ROWS - r0;
        if (rows > max_rows) rows = max_rows;
        featurize_kernel<<<(rows * 64 + 255) / 256, 256, 0, stream>>>(x, A, r0, rows);
        gemm_bt_kernel<<<dim3(O_DIM / BN, rows / BM), 256, 0, stream>>>(
            A, W, out + (size_t)r0 * O_DIM);
    }
}

// Round 3
// 216.041 us; speedup vs baseline: 1.0498x; 1.0241x over previous
//
#include <hip/hip_runtime.h>
#include <cstdint>
#include <cstddef>

#define B_ROWS 16384
#define D_DIM  512
#define O_DIM  512
#define K_DIM  4608    // 9 * 512: f=0 silu, f=1..8 spline basis
#define BM 128
#define BN 128
#define BK 32
#define ASTRIDE 40     // padded A-tile row stride (bf16): uniform bank pattern

typedef __bf16 bf16;
typedef __attribute__((ext_vector_type(8))) bf16  bf16x8;
typedef __attribute__((ext_vector_type(4))) float f32x4;

__device__ __forceinline__ void async_load16(const void* g, void* l) {
    __builtin_amdgcn_global_load_lds(
        (const __attribute__((address_space(1))) void*)g,
        (__attribute__((address_space(3))) void*)l,
        16, 0, 0);
}

// base_weight[O,D] + spline_weight[O,D,8] fp32 -> W[O, 4608] bf16, k = f*512 + i
__global__ void pack_w_kernel(const float* __restrict__ bw,
                              const float* __restrict__ sw,
                              bf16* __restrict__ W) {
    int idx = blockIdx.x * blockDim.x + threadIdx.x;   // over O*64
    if (idx >= O_DIM * 64) return;
    int o  = idx >> 6;
    int i0 = (idx & 63) * 8;

    bf16 ob[9][8];
    const float* bwp = bw + (size_t)o * D_DIM + i0;
#pragma unroll
    for (int e = 0; e < 8; e++) {
        ob[0][e] = (bf16)bwp[e];
        const float* sp = sw + ((size_t)o * D_DIM + i0 + e) * 8;
#pragma unroll
        for (int c = 0; c < 8; c++)
            ob[c + 1][e] = (bf16)sp[c];
    }
    bf16* row = W + (size_t)o * K_DIM + i0;
#pragma unroll
    for (int f = 0; f < 9; f++)
        *(bf16x8*)(row + (size_t)f * D_DIM) = *(const bf16x8*)ob[f];
}

// Fused: C[16384,512] = featurize(x) @ W^T, A never materialized in HBM.
// K-loop reordered: outer i-chunk (16 x 32-wide), inner f (9). Per i-chunk a
// thread loads 16 x floats, computes all 9 features/element into registers,
// then per f writes its A-tile slice via ds_write_b128 (stride 40 -> uniform
// banks) while W stages via global_load_lds into XOR-swizzled Bs (proven 0
// conflicts). MFMA accumulation order over k is irrelevant.
__global__ __launch_bounds__(256, 2)
void gemm_fused_kernel(const float* __restrict__ x, const bf16* __restrict__ W,
                       float* __restrict__ C) {
    __shared__ __align__(16) bf16 As[BM * ASTRIDE];  // 10 KB
    __shared__ __align__(16) bf16 Bs[BN * BK];       // 8 KB

    const int tid  = threadIdx.x;
    const int n0   = blockIdx.x * BN;
    const int m0   = blockIdx.y * BM;
    const int wave = tid >> 6;
    const int lane = tid & 63;
    const int wm   = (wave & 1) * 64;
    const int wn   = (wave >> 1) * 64;
    const int l15  = lane & 15;
    const int quad = lane >> 4;

    // ---- A-tile compute assignment: thread owns (row r, 16 i's of half h)
    const int r = tid >> 1;            // 0..127
    const int h = tid & 1;             // i-half within 32-chunk
    const float* xrow = x + (size_t)(m0 + r) * D_DIM + h * 16;
    bf16* awr = As + r * ASTRIDE + h * 16;

    // ---- Bs staging (unchanged from proven R2 kernel): XOR-swizzled chunks
    const int sr    = tid >> 2;                           // 0..63
    const int sc    = ((tid & 3) ^ ((sr >> 1) & 3)) * 8;  // swizzled global chunk
    const bf16* gB0 = W + (size_t)(n0 + sr) * K_DIM + sc;
    const bf16* gB1 = gB0 + (size_t)64 * K_DIM;
    bf16* lB0 = Bs + tid * 8;
    bf16* lB1 = Bs + tid * 8 + 2048;

    const int swz  = (l15 >> 1) & 3;
    const int aoff = (wm + l15) * ASTRIDE + quad * 8;
    const int boff = (wn + l15) * BK + (quad ^ swz) * 8;

    f32x4 acc[4][4] = {};
    const float s6 = 1.0f / 6.0f;

    for (int i0c = 0; i0c < D_DIM; i0c += 32) {
        // load this thread's 16 x values
        float4 xq0 = ((const float4*)(xrow + i0c))[0];
        float4 xq1 = ((const float4*)(xrow + i0c))[1];
        float4 xq2 = ((const float4*)(xrow + i0c))[2];
        float4 xq3 = ((const float4*)(xrow + i0c))[3];
        float xe[16] = {xq0.x, xq0.y, xq0.z, xq0.w, xq1.x, xq1.y, xq1.z, xq1.w,
                        xq2.x, xq2.y, xq2.z, xq2.w, xq3.x, xq3.y, xq3.z, xq3.w};

        __attribute__((aligned(16))) bf16 vals[9][16];
#pragma unroll
        for (int e = 0; e < 16; e++) {
            float xv = xe[e];
            vals[0][e] = (bf16)(xv / (1.0f + __expf(-xv)));   // silu

            // uniform cubic B-spline, knots g[j] = 0.4*j - 3.2
            float xn = fminf(fmaxf(xv, -2.0f), 2.0f);
            float t  = (xn + 3.2f) * 2.5f;                    // in [3,13]
            float ft = floorf(t);
            int   j0 = (int)ft;
            float u  = t - ft;
            float u2 = u * u, u3 = u2 * u;
            float omu = 1.0f - u;
            float w0 = omu * omu * omu * s6;
            float w1 = (3.0f * u3 - 6.0f * u2 + 4.0f) * s6;
            float w2 = (-3.0f * u3 + 3.0f * u2 + 3.0f * u + 1.0f) * s6;
            float w3 = u3 * s6;
            // channel j (0..7) gets w_{j-j0+3}; j0>=11 -> all c<0 -> zero,
            // j0>=3 always, so no explicit valid flag needed.
#pragma unroll
            for (int j = 0; j < 8; j++) {
                int c = j - j0 + 3;
                float v = 0.0f;
                v = (c == 0) ? w0 : v;
                v = (c == 1) ? w1 : v;
                v = (c == 2) ? w2 : v;
                v = (c == 3) ? w3 : v;
                vals[j + 1][e] = (bf16)v;
            }
        }

#pragma unroll
        for (int f = 0; f < 9; f++) {
            const size_t koff = (size_t)f * D_DIM + i0c;
            async_load16(gB0 + koff, lB0);
            async_load16(gB1 + koff, lB1);
            *(bf16x8*)(awr)     = *(const bf16x8*)&vals[f][0];
            *(bf16x8*)(awr + 8) = *(const bf16x8*)&vals[f][8];
            __syncthreads();   // drains lgkm (A writes) + vm (W async) before barrier

            bf16x8 af[4], bfr[4];
#pragma unroll
            for (int tt = 0; tt < 4; tt++)
                af[tt] = *(const bf16x8*)(As + aoff + tt * 16 * ASTRIDE);
#pragma unroll
            for (int tt = 0; tt < 4; tt++)
                bfr[tt] = *(const bf16x8*)(Bs + boff + tt * 16 * BK);

#pragma unroll
            for (int im = 0; im < 4; im++)
#pragma unroll
                for (int jn = 0; jn < 4; jn++)
                    acc[im][jn] = __builtin_amdgcn_mfma_f32_16x16x32_bf16(
                        af[im], bfr[jn], acc[im][jn], 0, 0, 0);
            __syncthreads();
        }
    }

    // C/D layout: col = lane&15, row = quad*4 + reg   [measured m89/m91]
#pragma unroll
    for (int im = 0; im < 4; im++) {
        const int rbase = m0 + wm + im * 16 + quad * 4;
#pragma unroll
        for (int jn = 0; jn < 4; jn++) {
            const int col = n0 + wn + jn * 16 + l15;
#pragma unroll
            for (int rr = 0; rr < 4; rr++)
                C[(size_t)(rbase + rr) * O_DIM + col] = acc[im][jn][rr];
        }
    }
}

extern "C" void kernel_launch(void* const* d_in, const int* in_sizes, int n_in,
                              void* d_out, int out_size, void* d_ws, size_t ws_size,
                              hipStream_t stream) {
    const float* x  = (const float*)d_in[0];
    const float* bw = (const float*)d_in[1];
    const float* sw = (const float*)d_in[2];
    float* out = (float*)d_out;

    const size_t Wbytes = (size_t)O_DIM * K_DIM * sizeof(bf16);  // 4.7 MB
    if (ws_size < Wbytes) return;
    bf16* W = (bf16*)d_ws;

    pack_w_kernel<<<(O_DIM * 64 + 255) / 256, 256, 0, stream>>>(bw, sw, W);
    gemm_fused_kernel<<<dim3(O_DIM / BN, B_ROWS / BM), 256, 0, stream>>>(x, W, out);
}

// Round 5
// 190.976 us; speedup vs baseline: 1.1876x; 1.1312x over previous
//
#include <hip/hip_runtime.h>
#include <cstdint>
#include <cstddef>
#include <type_traits>

#define B_ROWS 16384
#define D_DIM  512
#define O_DIM  512
#define K_DIM  4608    // 9 * 512: f=0 silu, f=1..8 spline basis
#define BM 64
#define BN 256
#define BK 32

typedef __bf16 bf16;
typedef __attribute__((ext_vector_type(8))) bf16  bf16x8;
typedef __attribute__((ext_vector_type(4))) float f32x4;

__device__ __forceinline__ void async_load16(const void* g, void* l) {
    __builtin_amdgcn_global_load_lds(
        (const __attribute__((address_space(1))) void*)g,
        (__attribute__((address_space(3))) void*)l,
        16, 0, 0);
}

__device__ __forceinline__ uint32_t pk2(float a, float b) {
    uint16_t ua = __builtin_bit_cast(uint16_t, (__bf16)a);
    uint16_t ub = __builtin_bit_cast(uint16_t, (__bf16)b);
    return (uint32_t)ua | ((uint32_t)ub << 16);
}

// Spline channels b0..b7 for one element as 4 packed bf16 pair-regs.
// out[j] = w_{j-s}, s = j0-3: implemented as 128-bit shift of [w3:w2:w1:w0]
// by 16*s bits (s in 0..10; s>=8 -> all zero, matches ref for x>=1.2).
__device__ __forceinline__ void spline_pairs(float xv, uint32_t out[4]) {
    float xn = fminf(fmaxf(xv, -2.0f), 2.0f);
    float t  = (xn + 3.2f) * 2.5f;        // in [3,13]
    int   j0 = (int)t;                    // t>0 so trunc==floor
    float u  = t - (float)j0;
    float u2 = u * u, u3 = u2 * u, omu = 1.0f - u;
    const float s6 = 1.0f / 6.0f;
    float w0 = omu * omu * omu * s6;
    float w1 = (3.0f * u3 - 6.0f * u2 + 4.0f) * s6;
    float w2 = (-3.0f * u3 + 3.0f * u2 + 3.0f * u + 1.0f) * s6;
    float w3 = u3 * s6;
    uint64_t W64 = ((uint64_t)pk2(w2, w3) << 32) | pk2(w0, w1);
    int sh = (j0 - 3) * 16;               // 0..160
    uint64_t lo = W64 << (sh & 63);       // for sh in [64,128): == W64 << (sh-64)
    uint64_t hi = W64 >> ((64 - sh) & 63);
    uint32_t lo_lo = (uint32_t)lo, lo_hi = (uint32_t)(lo >> 32);
    uint32_t hi_lo = (uint32_t)hi, hi_hi = (uint32_t)(hi >> 32);
    bool lt64 = sh < 64, eq0 = (sh == 0), lt128 = sh < 128;
    out[0] = lt64 ? lo_lo : 0u;
    out[1] = lt64 ? lo_hi : 0u;
    out[2] = lt64 ? (eq0 ? 0u : hi_lo) : (lt128 ? lo_lo : 0u);
    out[3] = lt64 ? (eq0 ? 0u : hi_hi) : (lt128 ? lo_hi : 0u);
}

// base_weight[O,D] + spline_weight[O,D,8] fp32 -> W[O, 4608] bf16, k = f*512 + i
__global__ void pack_w_kernel(const float* __restrict__ bw,
                              const float* __restrict__ sw,
                              bf16* __restrict__ W) {
    int idx = blockIdx.x * blockDim.x + threadIdx.x;   // over O*64
    if (idx >= O_DIM * 64) return;
    int o  = idx >> 6;
    int i0 = (idx & 63) * 8;

    bf16 ob[9][8];
    const float* bwp = bw + (size_t)o * D_DIM + i0;
#pragma unroll
    for (int e = 0; e < 8; e++) {
        ob[0][e] = (bf16)bwp[e];
        const float* sp = sw + ((size_t)o * D_DIM + i0 + e) * 8;
#pragma unroll
        for (int c = 0; c < 8; c++)
            ob[c + 1][e] = (bf16)sp[c];
    }
    bf16* row = W + (size_t)o * K_DIM + i0;
#pragma unroll
    for (int f = 0; f < 9; f++)
        *(bf16x8*)(row + (size_t)f * D_DIM) = *(const bf16x8*)ob[f];
}

// Fused KAN GEMM, double-buffered LDS, 1 barrier per k-step (145 total).
// Step (c,f): consume buf[(c+f)&1]; produce As/Bs for step+1 into buf^1.
// Featurize pipelined: chunk c+1's element e computed at step (c,e+1); silu
// at (c,8). XOR-swizzled LDS slots (per-16-lane-phase-uniform banks).
// R5 fix: Bs round stride is 2048 ELEMENTS (64 rows x 32 k = 4096 B), was
// 4096 elements -> OOB LDS writes past Bs -> clobber/NaN.
__global__ __launch_bounds__(256, 2)
void gemm_fused_kernel(const float* __restrict__ x, const bf16* __restrict__ W,
                       float* __restrict__ C) {
    __shared__ __align__(16) bf16 As[2][BM * BK];    // 2 x 4 KB
    __shared__ __align__(16) bf16 Bs[2][BN * BK];    // 2 x 16 KB

    const int tid  = threadIdx.x;
    const int n0   = blockIdx.x * BN;
    const int m0   = blockIdx.y * BM;
    const int wave = tid >> 6;
    const int lane = tid & 63;
    const int wn   = wave * 64;          // wave tile 64(all rows) x 64
    const int l15  = lane & 15;
    const int quad = lane >> 4;

    // featurize: thread owns (row rA, 8 i's at quarter q8 of the 32-chunk)
    const int rA = tid >> 2;             // 0..63
    const int q8 = tid & 3;
    const float* xrow = x + (size_t)(m0 + rA) * D_DIM + q8 * 8;
    const int aslot = q8 ^ ((rA >> 1) & 3);              // XOR slot swizzle
    bf16* aw0 = &As[0][rA * BK + aslot * 8];
    bf16* aw1 = &As[1][rA * BK + aslot * 8];

    // Bs staging: 4 rounds of 64 rows (2048 elements each), XOR-swizzled slot
    const int sr = tid >> 2;
    const int sc = ((tid & 3) ^ ((sr >> 1) & 3)) * 8;
    const bf16* gB = W + (size_t)(n0 + sr) * K_DIM + sc; // +j*64*K_DIM per round
    bf16* lb0 = &Bs[0][tid * 8];
    bf16* lb1 = &Bs[1][tid * 8];

    const int swz  = (l15 >> 1) & 3;
    const int aoff = l15 * BK + (quad ^ swz) * 8;
    const int boff = (wn + l15) * BK + (quad ^ swz) * 8;

    f32x4 acc[4][4] = {};
    uint32_t vpk[2][4][8];   // [chunk parity][channel-pair][element]
    float xe[8];

    // ---- prologue: chunk 0 features + step-(0,0) buffers ----
    {
        float4 a = *(const float4*)xrow;
        float4 b = *(const float4*)(xrow + 4);
        xe[0]=a.x; xe[1]=a.y; xe[2]=a.z; xe[3]=a.w;
        xe[4]=b.x; xe[5]=b.y; xe[6]=b.z; xe[7]=b.w;
#pragma unroll
        for (int e = 0; e < 8; e++) {
            uint32_t o4[4];
            spline_pairs(xe[e], o4);
            vpk[0][0][e]=o4[0]; vpk[0][1][e]=o4[1];
            vpk[0][2][e]=o4[2]; vpk[0][3][e]=o4[3];
        }
        float sl[8];
#pragma unroll
        for (int e = 0; e < 8; e++)
            sl[e] = xe[e] * __builtin_amdgcn_rcpf(1.0f + __expf(-xe[e]));
        uint32_t o[4] = {pk2(sl[0],sl[1]), pk2(sl[2],sl[3]),
                         pk2(sl[4],sl[5]), pk2(sl[6],sl[7])};
        *(uint4*)aw0 = *(const uint4*)o;
#pragma unroll
        for (int j = 0; j < 4; j++)
            async_load16(gB + (size_t)j * 64 * K_DIM, lb0 + j * 2048);
    }
    __syncthreads();

    auto chunk_body = [&](auto pcv, int c) {
        constexpr int PC = decltype(pcv)::value;
#pragma unroll
        for (int f = 0; f < 9; f++) {
            const bf16* Asr = As[(PC + f) & 1];
            const bf16* Bsr = Bs[(PC + f) & 1];
            bf16* lbn = ((PC + f) & 1) ? lb0 : lb1;   // next buffer
            bf16* awn = ((PC + f) & 1) ? aw0 : aw1;
            const bool haveNext = !(c == 15 && f == 8);

            // prefetch Bs for next step (gets one full step of flight)
            if (haveNext) {
                int koff = (f < 8) ? ((f + 1) * D_DIM + c * 32) : ((c + 1) * 32);
#pragma unroll
                for (int j = 0; j < 4; j++)
                    async_load16(gB + (size_t)j * 64 * K_DIM + koff, lbn + j * 2048);
            }
            // x prefetch for chunk c+1 (barrier drain at end of step covers it)
            if (f == 0 && c < 15) {
                float4 a = *(const float4*)(xrow + (c + 1) * 32);
                float4 b = *(const float4*)(xrow + (c + 1) * 32 + 4);
                xe[0]=a.x; xe[1]=a.y; xe[2]=a.z; xe[3]=a.w;
                xe[4]=b.x; xe[5]=b.y; xe[6]=b.z; xe[7]=b.w;
            }
            // pipelined featurize: one element of chunk c+1 per step
            if (f >= 1 && c < 15) {
                uint32_t o4[4];
                spline_pairs(xe[f - 1], o4);
                vpk[PC ^ 1][0][f-1]=o4[0]; vpk[PC ^ 1][1][f-1]=o4[1];
                vpk[PC ^ 1][2][f-1]=o4[2]; vpk[PC ^ 1][3][f-1]=o4[3];
            }
            // As write for next step: channel b_f of chunk c, or silu of c+1
            if (haveNext) {
                uint32_t o[4];
                if (f < 8) {
                    const int pr = f >> 1;
#pragma unroll
                    for (int m = 0; m < 4; m++) {
                        uint32_t lo = vpk[PC][pr][2*m], hi = vpk[PC][pr][2*m+1];
                        o[m] = (f & 1) ? ((lo >> 16) | (hi & 0xFFFF0000u))
                                       : ((lo & 0xFFFFu) | (hi << 16));
                    }
                } else {
                    float sl[8];
#pragma unroll
                    for (int e = 0; e < 8; e++)
                        sl[e] = xe[e] * __builtin_amdgcn_rcpf(1.0f + __expf(-xe[e]));
                    o[0]=pk2(sl[0],sl[1]); o[1]=pk2(sl[2],sl[3]);
                    o[2]=pk2(sl[4],sl[5]); o[3]=pk2(sl[6],sl[7]);
                }
                *(uint4*)awn = *(const uint4*)o;
            }

            // consume current buffers
            bf16x8 af[4], bfr[4];
#pragma unroll
            for (int tt = 0; tt < 4; tt++)
                af[tt] = *(const bf16x8*)(Asr + aoff + tt * 16 * BK);
#pragma unroll
            for (int tt = 0; tt < 4; tt++)
                bfr[tt] = *(const bf16x8*)(Bsr + boff + tt * 16 * BK);
#pragma unroll
            for (int im = 0; im < 4; im++)
#pragma unroll
                for (int jn = 0; jn < 4; jn++)
                    acc[im][jn] = __builtin_amdgcn_mfma_f32_16x16x32_bf16(
                        af[im], bfr[jn], acc[im][jn], 0, 0, 0);
            __syncthreads();
        }
    };

    for (int cc = 0; cc < 16; cc += 2) {
        chunk_body(std::integral_constant<int,0>{}, cc);
        chunk_body(std::integral_constant<int,1>{}, cc + 1);
    }

    // C/D layout: col = lane&15, row = quad*4 + reg   [measured m89/m91]
#pragma unroll
    for (int im = 0; im < 4; im++) {
        const int rbase = m0 + im * 16 + quad * 4;
#pragma unroll
        for (int jn = 0; jn < 4; jn++) {
            const int col = n0 + wn + jn * 16 + l15;
#pragma unroll
            for (int rr = 0; rr < 4; rr++)
                C[(size_t)(rbase + rr) * O_DIM + col] = acc[im][jn][rr];
        }
    }
}

extern "C" void kernel_launch(void* const* d_in, const int* in_sizes, int n_in,
                              void* d_out, int out_size, void* d_ws, size_t ws_size,
                              hipStream_t stream) {
    const float* x  = (const float*)d_in[0];
    const float* bw = (const float*)d_in[1];
    const float* sw = (const float*)d_in[2];
    float* out = (float*)d_out;

    const size_t Wbytes = (size_t)O_DIM * K_DIM * sizeof(bf16);  // 4.7 MB
    if (ws_size < Wbytes) return;
    bf16* W = (bf16*)d_ws;

    pack_w_kernel<<<(O_DIM * 64 + 255) / 256, 256, 0, stream>>>(bw, sw, W);
    gemm_fused_kernel<<<dim3(O_DIM / BN, B_ROWS / BM), 256, 0, stream>>>(x, W, out);
}